// Round 4
// baseline (993.428 us; speedup 1.0000x reference)
//
#include <hip/hip_runtime.h>
#include <hip/hip_bf16.h>

#define L_ 4096
#define D_ 1024
#define H_ 16
#define HD_ 64
#define NW_ 8
#define WIN_ 512
#define TD (3*D_)

typedef __attribute__((ext_vector_type(8))) short bf16x8;
typedef __attribute__((ext_vector_type(4))) float f32x4;

__device__ __forceinline__ f32x4 mfma16(bf16x8 a, bf16x8 b, f32x4 c) {
    return __builtin_amdgcn_mfma_f32_16x16x32_bf16(a, b, c, 0, 0, 0);
}

__device__ __forceinline__ short f2bfs(float f) {
    __hip_bfloat16 h = __float2bfloat16(f);
    return *reinterpret_cast<short*>(&h);
}

// NaN-laundering clamp: fmaxf(NaN, -c) == -c, so NaN maps to -c (finite).
__device__ __forceinline__ float lclamp(float v, float c) {
    return fminf(fmaxf(v, -c), c);
}

// rotary additive term for (seq pos l, feature d), exact fp32
__device__ __forceinline__ float rot_add(const float* rf, int l, int d) {
    const int j = d & 511;
    const float r = rf[j];
    const float inv = exp2f((float)j * 0.02595256324130752f); // 10000^(j/512)
    const float ang = r * (float)l / inv;
    return (d < 512) ? cosf(ang) : sinf(ang);
}

// ---------------------------------------------------------------------------
// x1b = bf16( x + cat(cos(ang), sin(ang)) ),  x fp32 in, bf16 out
// ---------------------------------------------------------------------------
__global__ __launch_bounds__(256) void rotary_k(
    const float* __restrict__ x,
    const float* __restrict__ rf,
    __hip_bfloat16* __restrict__ x1b)
{
    const int idx = blockIdx.x * 256 + threadIdx.x;   // over L*D
    const int l = idx >> 10;
    const int d = idx & 1023;
    const float v = x[idx] + rot_add(rf, l, d);
    x1b[idx] = __float2bfloat16(lclamp(v, 1.0e4f));
}

// ---------------------------------------------------------------------------
// C[M,N] = A[M,1024](bf16) @ W[N,1024]^T(fp32->bf16) + bias[N](fp32)
//          (+ residual), out bf16 (Cb) or fp32 (Cf).
// residMode 1: residual = x[row,col] + rotary(row,col) in exact fp32.
// Per-window weights: pointer advanced by (m0/512)*stride.
// 128x128 tile, 4 waves (2x2 of 64x64), BK=32, 16x16x32 bf16 MFMA.
// ---------------------------------------------------------------------------
__global__ __launch_bounds__(256) void gemm_bt(
    const __hip_bfloat16* __restrict__ A,
    const float* __restrict__ Wt,
    const float* __restrict__ bias,
    const float* __restrict__ xin,   // for residMode
    const float* __restrict__ rf,    // for residMode
    int residMode,
    __hip_bfloat16* __restrict__ Cb,
    float* __restrict__ Cf,
    int N, int wStrideW, int wStrideB)
{
    const int K = D_;
    const int m0 = blockIdx.y * 128;
    const int n0 = blockIdx.x * 128;
    const int win = m0 / WIN_;
    const float* Wp = Wt + (size_t)win * (size_t)wStrideW;
    const float* Bp = bias + (size_t)win * (size_t)wStrideB;

    __shared__ __align__(16) short As[128 * 40];   // +8 pad
    __shared__ __align__(16) short Bs[128 * 40];

    const int tid  = threadIdx.x;
    const int lane = tid & 63;
    const int wave = tid >> 6;
    const int wm = (wave & 1) * 64;
    const int wn = (wave >> 1) * 64;
    const int lrow = lane & 15;
    const int kg   = lane >> 4;

    const f32x4 zero4 = {0.f, 0.f, 0.f, 0.f};
    f32x4 acc[4][4];
    #pragma unroll
    for (int i = 0; i < 4; i++)
        #pragma unroll
        for (int jj = 0; jj < 4; jj++) acc[i][jj] = zero4;

    for (int k0 = 0; k0 < K; k0 += 32) {
        __syncthreads();
        #pragma unroll
        for (int c = tid; c < 512; c += 256) {
            const int row = c >> 2, part = c & 3;
            // A: bf16, direct 16B copy (8 elems)
            *(uint4*)&As[row * 40 + part * 8] =
                *(const uint4*)&A[(size_t)(m0 + row) * K + k0 + part * 8];
            // W: fp32 -> bf16 convert (8 elems = two float4)
            const float4 w0 = *(const float4*)&Wp[(size_t)(n0 + row) * K + k0 + part * 8];
            const float4 w1 = *(const float4*)&Wp[(size_t)(n0 + row) * K + k0 + part * 8 + 4];
            short* bd = &Bs[row * 40 + part * 8];
            bd[0] = f2bfs(w0.x); bd[1] = f2bfs(w0.y);
            bd[2] = f2bfs(w0.z); bd[3] = f2bfs(w0.w);
            bd[4] = f2bfs(w1.x); bd[5] = f2bfs(w1.y);
            bd[6] = f2bfs(w1.z); bd[7] = f2bfs(w1.w);
        }
        __syncthreads();
        bf16x8 af[4], bfr[4];
        #pragma unroll
        for (int i = 0; i < 4; i++)
            af[i] = *(const bf16x8*)&As[(wm + i * 16 + lrow) * 40 + kg * 8];
        #pragma unroll
        for (int jj = 0; jj < 4; jj++)
            bfr[jj] = *(const bf16x8*)&Bs[(wn + jj * 16 + lrow) * 40 + kg * 8];
        #pragma unroll
        for (int i = 0; i < 4; i++)
            #pragma unroll
            for (int jj = 0; jj < 4; jj++)
                acc[i][jj] = mfma16(af[i], bfr[jj], acc[i][jj]);
    }

    // C/D layout: row = kg*4 + r, col = lrow  (within each 16x16 tile)
    #pragma unroll
    for (int jj = 0; jj < 4; jj++) {
        const int col = n0 + wn + jj * 16 + lrow;
        const float bv = Bp[col];
        #pragma unroll
        for (int i = 0; i < 4; i++) {
            #pragma unroll
            for (int r = 0; r < 4; r++) {
                const int row = m0 + wm + i * 16 + kg * 4 + r;
                float v = acc[i][jj][r] + bv;
                if (residMode) {
                    v += xin[(size_t)row * D_ + col] + rot_add(rf, row, col);
                }
                v = lclamp(v, 1.0e4f);
                if (Cf) Cf[(size_t)row * N + col] = v;
                else    Cb[(size_t)row * N + col] = __float2bfloat16(v);
            }
        }
    }
}

// ---------------------------------------------------------------------------
// Flash attention over one (window, head, 16-row Q tile). 1 wave per block.
// qkv: [L, 3*D] bf16 (q | k | v).  o: [L, D] bf16. scale = HD^-0.5 = 0.125.
// ---------------------------------------------------------------------------
__global__ __launch_bounds__(64) void attn_k(
    const __hip_bfloat16* __restrict__ qkv,
    __hip_bfloat16* __restrict__ o,
    int Sw)
{
    const int lane = threadIdx.x;
    const int lrow = lane & 15;
    const int kg   = lane >> 4;
    const int h = blockIdx.y;
    const int wbase = blockIdx.z * Sw;
    const int q0 = wbase + blockIdx.x * 16;

    const size_t ld = TD;
    const __hip_bfloat16* Q  = qkv + (size_t)q0 * ld + h * HD_;
    const __hip_bfloat16* Kp = qkv + (size_t)wbase * ld + D_ + h * HD_;
    const short* Vs = reinterpret_cast<const short*>(qkv)
                      + (size_t)wbase * ld + 2 * D_ + h * HD_;

    __shared__ __align__(16) short Ps[16 * 32];   // P tile: [16 q][32 keys]

    const bf16x8 qf0 = *(const bf16x8*)&Q[(size_t)lrow * ld + kg * 8];
    const bf16x8 qf1 = *(const bf16x8*)&Q[(size_t)lrow * ld + 32 + kg * 8];

    const f32x4 zero4 = {0.f, 0.f, 0.f, 0.f};
    float m_[4], l_[4], alpha[4];
    f32x4 oacc[4];
    #pragma unroll
    for (int r = 0; r < 4; r++) { m_[r] = -1e30f; l_[r] = 0.f; }
    #pragma unroll
    for (int t = 0; t < 4; t++) oacc[t] = zero4;

    for (int c = 0; c < Sw; c += 32) {
        const __hip_bfloat16* K0 = Kp + (size_t)(c + lrow) * ld;
        const __hip_bfloat16* K1 = Kp + (size_t)(c + 16 + lrow) * ld;
        bf16x8 ka0 = *(const bf16x8*)&K0[kg * 8];
        bf16x8 ka1 = *(const bf16x8*)&K0[32 + kg * 8];
        bf16x8 kb0 = *(const bf16x8*)&K1[kg * 8];
        bf16x8 kb1 = *(const bf16x8*)&K1[32 + kg * 8];

        f32x4 s0 = zero4, s1 = zero4;
        s0 = mfma16(qf0, ka0, s0);
        s0 = mfma16(qf1, ka1, s0);
        s1 = mfma16(qf0, kb0, s1);
        s1 = mfma16(qf1, kb1, s1);

        float mx[4];
        #pragma unroll
        for (int r = 0; r < 4; r++) {
            // scale + NaN-laundering clamp (|true scores| << 60)
            s0[r] = lclamp(s0[r] * 0.125f, 60.0f);
            s1[r] = lclamp(s1[r] * 0.125f, 60.0f);
            mx[r] = fmaxf(s0[r], s1[r]);
        }
        #pragma unroll
        for (int off = 1; off < 16; off <<= 1)
            #pragma unroll
            for (int r = 0; r < 4; r++)
                mx[r] = fmaxf(mx[r], __shfl_xor(mx[r], off, 64));

        float p0[4], p1[4], rs[4];
        #pragma unroll
        for (int r = 0; r < 4; r++) {
            const float mn = fmaxf(m_[r], mx[r]);
            alpha[r] = __expf(m_[r] - mn);
            p0[r] = __expf(s0[r] - mn);
            p1[r] = __expf(s1[r] - mn);
            rs[r] = p0[r] + p1[r];
            m_[r] = mn;
        }
        #pragma unroll
        for (int off = 1; off < 16; off <<= 1)
            #pragma unroll
            for (int r = 0; r < 4; r++)
                rs[r] += __shfl_xor(rs[r], off, 64);
        #pragma unroll
        for (int r = 0; r < 4; r++)
            l_[r] = l_[r] * alpha[r] + rs[r];
        #pragma unroll
        for (int t = 0; t < 4; t++)
            #pragma unroll
            for (int r = 0; r < 4; r++)
                oacc[t][r] *= alpha[r];

        // P: C-layout -> A-layout via LDS round-trip
        __syncthreads();
        #pragma unroll
        for (int r = 0; r < 4; r++) {
            Ps[(kg * 4 + r) * 32 + lrow]      = f2bfs(p0[r]);
            Ps[(kg * 4 + r) * 32 + 16 + lrow] = f2bfs(p1[r]);
        }
        __syncthreads();
        const bf16x8 pf = *(const bf16x8*)&Ps[lrow * 32 + kg * 8];

        #pragma unroll
        for (int t = 0; t < 4; t++) {
            short vt[8];
            const short* Vb = Vs + (size_t)(c + kg * 8) * ld + t * 16 + lrow;
            #pragma unroll
            for (int j = 0; j < 8; j++) vt[j] = Vb[(size_t)j * ld];
            bf16x8 vf;
            #pragma unroll
            for (int j = 0; j < 8; j++) vf[j] = vt[j];
            oacc[t] = mfma16(pf, vf, oacc[t]);
        }
    }

    #pragma unroll
    for (int t = 0; t < 4; t++) {
        #pragma unroll
        for (int r = 0; r < 4; r++) {
            const int row = q0 + kg * 4 + r;
            const int col = h * HD_ + t * 16 + lrow;
            o[(size_t)row * D_ + col] =
                __float2bfloat16(lclamp(oacc[t][r] / l_[r], 1.0e4f));
        }
    }
}

// ---------------------------------------------------------------------------
extern "C" void kernel_launch(void* const* d_in, const int* in_sizes, int n_in,
                              void* d_out, int out_size, void* d_ws, size_t ws_size,
                              hipStream_t stream)
{
    // ALL inputs are float32 (reference dtypes); output is float32.
    const float* x   = (const float*)d_in[0];
    const float* rf  = (const float*)d_in[1];
    const float* wwi = (const float*)d_in[2];
    const float* wbi = (const float*)d_in[3];
    const float* wwo = (const float*)d_in[4];
    const float* wbo = (const float*)d_in[5];
    const float* fwi = (const float*)d_in[6];
    const float* fbi = (const float*)d_in[7];
    const float* fwo = (const float*)d_in[8];
    const float* fbo = (const float*)d_in[9];

    // Workspace: 32 MiB. bf16 x1/x2 scratch lives in d_out's first 8 MiB
    // (d_out is 16 MiB fp32); dead before gemm7's final fp32 write.
    char* ws = (char*)d_ws;
    __hip_bfloat16* qkv = (__hip_bfloat16*)(ws);                 // [L,3D] 24 MiB
    __hip_bfloat16* ob  = (__hip_bfloat16*)(ws + (24u << 20));   // [L,D]   8 MiB
    __hip_bfloat16* xsc = (__hip_bfloat16*)d_out;                // [L,D] bf16 scratch

    // 1. rotary add -> x1 (bf16)
    rotary_k<<<dim3(L_ * D_ / 256), 256, 0, stream>>>(x, rf, xsc);

    // 2. per-window qkv = x1 @ win_w_in^T + win_b_in
    gemm_bt<<<dim3(TD / 128, L_ / 128), 256, 0, stream>>>(
        xsc, wwi, wbi, nullptr, nullptr, 0, qkv, nullptr, TD, TD * D_, TD);

    // 3. windowed attention (Sw = 512)
    attn_k<<<dim3(WIN_ / 16, H_, NW_), 64, 0, stream>>>(qkv, ob, WIN_);

    // 4. x2 = (x + rotary, exact fp32) + o @ win_w_out^T + win_b_out
    gemm_bt<<<dim3(D_ / 128, L_ / 128), 256, 0, stream>>>(
        ob, wwo, wbo, x, rf, 1, xsc, nullptr, D_, D_ * D_, D_);

    // 5. final qkv = x2 @ fin_w_in^T + fin_b_in
    gemm_bt<<<dim3(TD / 128, L_ / 128), 256, 0, stream>>>(
        xsc, fwi, fbi, nullptr, nullptr, 0, qkv, nullptr, TD, 0, 0);

    // 6. global attention (Sw = 4096)
    attn_k<<<dim3(L_ / 16, H_, 1), 64, 0, stream>>>(qkv, ob, L_);

    // 7. out = o @ fin_w_out^T + fin_b_out  -> d_out (fp32, final)
    gemm_bt<<<dim3(D_ / 128, L_ / 128), 256, 0, stream>>>(
        ob, fwo, fbo, nullptr, nullptr, 0, nullptr, (float*)d_out, D_, 0, 0);
}